// Round 1
// 461.627 us; speedup vs baseline: 1.1290x; 1.1290x over previous
//
#include <hip/hip_runtime.h>
#include <hip/hip_bf16.h>
#include <stdint.h>

// R9: pre-convert fp32 inputs to bf16 (one memory-bound pass), then GEMMs
// stage via __builtin_amdgcn_global_load_lds width=16 (ladder step 3:
// removes the VALU cvt+LDS-write from the K-loop; 517->874 TF measured on
// this exact 128x128/BK=32 structure). Attn unchanged from R8.
// Workspace (88 MB, aliased):
//   [0,48M)   qkv bf16
//   [48,64M)  x_bf (gemm1 A)  --later-->  y (attn out / gemm2 A)
//   [64,88M)  Wqkv_bf (gemm1 B) --later--> Wproj_bf (gemm2 B, first 8MB)

typedef __bf16 bf16x8 __attribute__((ext_vector_type(8)));
typedef float f32x4 __attribute__((ext_vector_type(4)));
typedef unsigned short u16x8 __attribute__((ext_vector_type(8)));
typedef unsigned short u16x4 __attribute__((ext_vector_type(4)));

__device__ __forceinline__ unsigned short f2bf(float f) {
  unsigned int u = __builtin_bit_cast(unsigned int, f);
  u += 0x7fff + ((u >> 16) & 1);   // RNE; values are finite
  return (unsigned short)(u >> 16);
}
__device__ __forceinline__ float bf2f(unsigned short u) {
  return __builtin_bit_cast(float, (unsigned int)u << 16);
}

__device__ __forceinline__ u16x8 cvt8(const float* p) {
  f32x4 lo = *(const f32x4*)p;
  f32x4 hi = *(const f32x4*)(p + 4);
  u16x8 r;
#pragma unroll
  for (int j = 0; j < 4; j++) { r[j] = f2bf(lo[j]); r[4 + j] = f2bf(hi[j]); }
  return r;
}

// async 16B global->LDS copy. LDS dest must be wave-uniform base; HW adds
// lane*16. Global src is per-lane.
__device__ __forceinline__ void gload16(const void* g, void* l) {
  __builtin_amdgcn_global_load_lds(
      (const __attribute__((address_space(1))) void*)g,
      (__attribute__((address_space(3))) void*)l, 16, 0, 0);
}

// ---------------------------------------------------------------------------
// fp32 -> bf16 bulk convert. n8 = element count / 8. Memory-bound.
// ---------------------------------------------------------------------------
__global__ __launch_bounds__(256) void f32_to_bf16(
    const float* __restrict__ src, unsigned short* __restrict__ dst, int n8) {
  int i = blockIdx.x * 256 + threadIdx.x;
  const int stride = gridDim.x * 256;
  for (; i < n8; i += stride) {
    u16x8 v = cvt8(src + (size_t)i * 8);
    *(u16x8*)&dst[(size_t)i * 8] = v;
  }
}

// ---------------------------------------------------------------------------
// GEMM: C[M][N] = A[M][K] @ B[N][K]^T. A/B bf16; C bf16 or fp32.
// 128x128 tile, BK=32, 256 threads (4 waves, each 64x64 as 4x4 of 16x16x32).
// Staging: global_load_lds dwordx4, linear LDS (layout matches wave-uniform
// base + lane*16 exactly: chunk c -> Alds[c*8..c*8+7]).
// ---------------------------------------------------------------------------
template <bool COF32>
__global__ __launch_bounds__(256) void gemm_bf(
    const unsigned short* __restrict__ A, const unsigned short* __restrict__ B,
    void* __restrict__ Cv, int M, int N, int K) {
  __shared__ __align__(16) unsigned short Alds[128 * 32];
  __shared__ __align__(16) unsigned short Blds[128 * 32];

  const int tid  = threadIdx.x;
  const int lane = tid & 63;
  const int w    = tid >> 6;
  const int ln   = lane & 15;
  const int kq   = lane >> 4;
  const int m0 = blockIdx.y * 128;
  const int n0 = blockIdx.x * 128;
  const int m_base = (w >> 1) * 64;
  const int n_base = (w & 1) * 64;

  f32x4 acc[4][4];
#pragma unroll
  for (int i = 0; i < 4; i++)
#pragma unroll
    for (int j = 0; j < 4; j++) acc[i][j] = {0.f, 0.f, 0.f, 0.f};

  const int c0 = tid;          // chunk ids: [0,256) and [256,512)
  const int c1 = tid + 256;
  const unsigned short* Ag0 = A + (size_t)(m0 + (c0 >> 2)) * K + (c0 & 3) * 8;
  const unsigned short* Ag1 = A + (size_t)(m0 + (c1 >> 2)) * K + (c1 & 3) * 8;
  const unsigned short* Bg0 = B + (size_t)(n0 + (c0 >> 2)) * K + (c0 & 3) * 8;
  const unsigned short* Bg1 = B + (size_t)(n0 + (c1 >> 2)) * K + (c1 & 3) * 8;
  // wave-uniform LDS bases: chunk c lands at byte c*16 (= element c*8)
  unsigned short* lA0 = &Alds[(size_t)w * 512];
  unsigned short* lA1 = &Alds[2048 + (size_t)w * 512];
  unsigned short* lB0 = &Blds[(size_t)w * 512];
  unsigned short* lB1 = &Blds[2048 + (size_t)w * 512];

  const int nk = K >> 5;
  for (int kt = 0; kt < nk; kt++) {
    const int ko = kt * 32;
    gload16(Ag0 + ko, lA0);
    gload16(Ag1 + ko, lA1);
    gload16(Bg0 + ko, lB0);
    gload16(Bg1 + ko, lB1);
    __syncthreads();   // compiler drains vmcnt(0) before s_barrier

    bf16x8 af[4], bfr[4];
#pragma unroll
    for (int i = 0; i < 4; i++)
      af[i] = *(const bf16x8*)&Alds[(m_base + i * 16 + ln) * 32 + kq * 8];
#pragma unroll
    for (int j = 0; j < 4; j++)
      bfr[j] = *(const bf16x8*)&Blds[(n_base + j * 16 + ln) * 32 + kq * 8];
#pragma unroll
    for (int i = 0; i < 4; i++)
#pragma unroll
      for (int j = 0; j < 4; j++)
        acc[i][j] = __builtin_amdgcn_mfma_f32_16x16x32_bf16(af[i], bfr[j], acc[i][j], 0, 0, 0);
    __syncthreads();
  }

  // Epilogue. C/D layout (m89): col = ln, row = kq*4 + r.
#pragma unroll
  for (int i = 0; i < 4; i++) {
    const int row_base = m0 + m_base + i * 16 + kq * 4;
#pragma unroll
    for (int j = 0; j < 4; j++) {
      const int col = n0 + n_base + j * 16 + ln;
#pragma unroll
      for (int r = 0; r < 4; r++) {
        const size_t idx = (size_t)(row_base + r) * N + col;
        if (COF32) ((float*)Cv)[idx] = acc[i][j][r];
        else       ((unsigned short*)Cv)[idx] = f2bf(acc[i][j][r]);
      }
    }
  }
}

// ---------------------------------------------------------------------------
// Transposed flash attention. qkv: [B*T][6144] bf16 (q|k|v, 2048 each).
// Block (qt,h,b): 64 q rows; wave w owns q rows q0+w*16+ln (one per lane).
// S^T = K.Q^T  : D[m=key=kq*4+r (per nt)][n=q=ln]
// O^T = V^T.P^T: D[m=d=nt*16+kq*4+r][n=q=ln]
// ---------------------------------------------------------------------------
#define TSEQ 2048
#define CDIM 2048
#define QKVLD 6144
#define DH 128
#define NEG_BIG (-1.0e30f)
#define K_LD 136
#define VT_LD 76
#define P_LD 72

__global__ __launch_bounds__(256) void attn(
    const unsigned short* __restrict__ qkv,
    unsigned short* __restrict__ y) {
  __shared__ __align__(16) unsigned short Klds[64 * K_LD];    // [key][d]
  __shared__ __align__(16) unsigned short Vt[DH * VT_LD];     // [d][key]
  __shared__ __align__(16) unsigned short Plds[4 * 16 * P_LD];// per-wave [q][key]

  const int tid  = threadIdx.x;
  const int lane = tid & 63;
  const int w    = tid >> 6;
  const int ln   = lane & 15;
  const int kq   = lane >> 4;
  const int qt = blockIdx.x;
  const int h  = blockIdx.y;
  const int b  = blockIdx.z;
  const int q0 = qt * 64;
  const int qrow = q0 + w * 16 + ln;      // this lane's q row (global in seq)

  const size_t baseQ = (size_t)b * TSEQ * QKVLD + (size_t)h * DH;
  const size_t baseK = baseQ + CDIM;
  const size_t baseV = baseQ + 2 * CDIM;

  // Q fragments (B-operand), pre-scaled by 1/sqrt(128).
  bf16x8 qf[4];
  {
    const float scale = 0.08838834764831845f;
    const unsigned short* qp = qkv + baseQ + (size_t)qrow * QKVLD + kq * 8;
#pragma unroll
    for (int kc = 0; kc < 4; kc++) {
      u16x8 raw = *(const u16x8*)(qp + kc * 32);
      u16x8 t;
#pragma unroll
      for (int j = 0; j < 8; j++) t[j] = f2bf(bf2f(raw[j]) * scale);
      qf[kc] = __builtin_bit_cast(bf16x8, t);
    }
  }

  // staging addresses
  const int kRow = tid >> 4;                 // K: key row base (16 rows/iter grp)
  const int kCol = (tid & 15) * 8;           // K: d offset
  const int vK4  = (tid & 15) * 4;           // V: 4 consecutive keys
  const int vD0  = (tid >> 4) * 8;           // V: 8 d elems
  const unsigned short* Kg = qkv + baseK + (size_t)kRow * QKVLD + kCol;
  const unsigned short* Vg = qkv + baseV + (size_t)vK4 * QKVLD + vD0;

  u16x8 kreg[4], vreg[4];
#pragma unroll
  for (int it = 0; it < 4; it++)
    kreg[it] = *(const u16x8*)(Kg + (size_t)(it * 16) * QKVLD);
#pragma unroll
  for (int r = 0; r < 4; r++)
    vreg[r] = *(const u16x8*)(Vg + (size_t)r * QKVLD);

  f32x4 o[8];
#pragma unroll
  for (int i = 0; i < 8; i++) o[i] = {0.f, 0.f, 0.f, 0.f};
  float m = NEG_BIG, l = 0.f;
  unsigned short* pw = &Plds[w * 16 * P_LD];

  for (int kt = 0; kt <= qt; kt++) {
    __syncthreads();  // previous iteration's LDS reads done

    // commit prefetched tile to LDS
#pragma unroll
    for (int it = 0; it < 4; it++)
      *(u16x8*)&Klds[(kRow + it * 16) * K_LD + kCol] = kreg[it];
#pragma unroll
    for (int j = 0; j < 8; j++) {
      u16x4 t = {vreg[0][j], vreg[1][j], vreg[2][j], vreg[3][j]};
      *(u16x4*)&Vt[(vD0 + j) * VT_LD + vK4] = t;
    }
    __syncthreads();

    // prefetch next tile (no wait; overlaps compute)
    if (kt < qt) {
      const size_t off = (size_t)(kt + 1) * 64 * QKVLD;
#pragma unroll
      for (int it = 0; it < 4; it++)
        kreg[it] = *(const u16x8*)(Kg + off + (size_t)(it * 16) * QKVLD);
#pragma unroll
      for (int r = 0; r < 4; r++)
        vreg[r] = *(const u16x8*)(Vg + off + (size_t)r * QKVLD);
    }

    // --- S^T = K Q^T : s[nt][r] = S[key = kt*64+nt*16+kq*4+r][q = qrow] ---
    f32x4 s[4];
#pragma unroll
    for (int nt = 0; nt < 4; nt++) {
      s[nt] = {0.f, 0.f, 0.f, 0.f};
#pragma unroll
      for (int kc = 0; kc < 4; kc++) {
        bf16x8 kb = *(const bf16x8*)&Klds[(nt * 16 + ln) * K_LD + kc * 32 + kq * 8];
        s[nt] = __builtin_amdgcn_mfma_f32_16x16x32_bf16(kb, qf[kc], s[nt], 0, 0, 0);
      }
    }

    // --- causal mask (only on the diagonal tile) ---
    if (kt == qt) {
      const int kbase = kt * 64 + kq * 4;
#pragma unroll
      for (int nt = 0; nt < 4; nt++)
#pragma unroll
        for (int r = 0; r < 4; r++)
          if (kbase + nt * 16 + r > qrow) s[nt][r] = NEG_BIG;
    }

    // --- per-lane online softmax (lane owns one q row) ---
    float mt;
    {
      f32x4 t01 = {fmaxf(s[0][0], s[0][1]), fmaxf(s[0][2], s[0][3]),
                   fmaxf(s[1][0], s[1][1]), fmaxf(s[1][2], s[1][3])};
      f32x4 t23 = {fmaxf(s[2][0], s[2][1]), fmaxf(s[2][2], s[2][3]),
                   fmaxf(s[3][0], s[3][1]), fmaxf(s[3][2], s[3][3])};
      f32x4 t = {fmaxf(t01[0], t01[1]), fmaxf(t01[2], t01[3]),
                 fmaxf(t23[0], t23[1]), fmaxf(t23[2], t23[3])};
      mt = fmaxf(fmaxf(t[0], t[1]), fmaxf(t[2], t[3]));
    }
    mt = fmaxf(mt, __shfl_xor(mt, 16, 64));
    mt = fmaxf(mt, __shfl_xor(mt, 32, 64));
    const float mn = fmaxf(m, mt);
    const float alpha = __expf(m - mn);
    m = mn;

    float ps = 0.f;
#pragma unroll
    for (int nt = 0; nt < 4; nt++) {
      u16x4 pbits;
#pragma unroll
      for (int r = 0; r < 4; r++) {
        const float p = __expf(s[nt][r] - mn);
        ps += p;
        pbits[r] = f2bf(p);
      }
      *(u16x4*)&pw[ln * P_LD + nt * 16 + kq * 4] = pbits;  // P[q=ln][key]
    }
    ps += __shfl_xor(ps, 16, 64);
    ps += __shfl_xor(ps, 32, 64);
    l = l * alpha + ps;

#pragma unroll
    for (int i = 0; i < 8; i++)
#pragma unroll
      for (int r = 0; r < 4; r++) o[i][r] *= alpha;

    // --- O^T += V^T P^T (P read back as B-frag; same-wave DS in order) ---
    bf16x8 pa[2];
#pragma unroll
    for (int kc = 0; kc < 2; kc++)
      pa[kc] = *(const bf16x8*)&pw[ln * P_LD + kc * 32 + kq * 8];
#pragma unroll
    for (int nt = 0; nt < 8; nt++)
#pragma unroll
      for (int kc = 0; kc < 2; kc++) {
        bf16x8 vb = *(const bf16x8*)&Vt[(nt * 16 + ln) * VT_LD + kc * 32 + kq * 8];
        o[nt] = __builtin_amdgcn_mfma_f32_16x16x32_bf16(vb, pa[kc], o[nt], 0, 0, 0);
      }
  }

  // --- epilogue: o[nt][r] = O[q=qrow][d = nt*16 + kq*4 + r] ---
  const float inv = 1.f / l;
  unsigned short* yp = y + (size_t)(b * TSEQ + qrow) * CDIM + (size_t)h * DH + kq * 4;
#pragma unroll
  for (int nt = 0; nt < 8; nt++) {
    u16x4 ov;
#pragma unroll
    for (int r = 0; r < 4; r++) ov[r] = f2bf(o[nt][r] * inv);
    *(u16x4*)(yp + nt * 16) = ov;
  }
}

extern "C" void kernel_launch(void* const* d_in, const int* in_sizes, int n_in,
                              void* d_out, int out_size, void* d_ws, size_t ws_size,
                              hipStream_t stream) {
  const float* x     = (const float*)d_in[0];  // fp32 [4096][2048]
  const float* Wqkv  = (const float*)d_in[1];  // fp32 [6144][2048]
  const float* Wproj = (const float*)d_in[2];  // fp32 [2048][2048]
  void* out = d_out;                                   // fp32 [4096][2048]

  unsigned short* qkv = (unsigned short*)d_ws;         // bf16, 48MB
  unsigned short* y   = qkv + (size_t)4096 * 6144;     // bf16, 16MB (aliases x_bf)
  unsigned short* xbf = y;                             // x_bf dead before attn writes y
  unsigned short* wbf = y + (size_t)4096 * 2048;       // 24MB (Wqkv_bf, then Wproj_bf)

  f32_to_bf16<<<dim3(2048), 256, 0, stream>>>(x, xbf, (4096 * 2048) / 8);
  f32_to_bf16<<<dim3(2048), 256, 0, stream>>>(Wqkv, wbf, (6144 * 2048) / 8);
  gemm_bf<false><<<dim3(48, 32), 256, 0, stream>>>(xbf, wbf, qkv, 4096, 6144, 2048);
  f32_to_bf16<<<dim3(2048), 256, 0, stream>>>(Wproj, wbf, (2048 * 2048) / 8);  // Wqkv_bf dead
  attn<<<dim3(32, 16, 2), 256, 0, stream>>>(qkv, y);
  gemm_bf<true><<<dim3(16, 32), 256, 0, stream>>>(y, wbf, out, 4096, 2048, 2048);
}

// Round 2
// 393.423 us; speedup vs baseline: 1.3248x; 1.1734x over previous
//
#include <hip/hip_runtime.h>
#include <hip/hip_bf16.h>
#include <stdint.h>

// R10: attn restructured QBLK 64->128 (8 waves, 512 thr) over same 64-key
// staged K/V tile: staging+barriers+K/V-refetch halve per unit compute.
// Grid = 512 blocks = exactly 2/CU (all co-resident); balanced decode
// (b=0 half qb-descending, b=1 half qb-ascending -> per-CU pair sums to
// constant work). Wave-uniform skip of fully-masked tiles. T13 defer-max
// skips O-rescale when max growth <= 8. GEMMs unchanged from R9.
// Workspace (88 MB, aliased):
//   [0,48M)   qkv bf16
//   [48,64M)  x_bf (gemm1 A)  --later-->  y (attn out / gemm2 A)
//   [64,88M)  Wqkv_bf (gemm1 B) --later--> Wproj_bf (gemm2 B, first 8MB)

typedef __bf16 bf16x8 __attribute__((ext_vector_type(8)));
typedef float f32x4 __attribute__((ext_vector_type(4)));
typedef unsigned short u16x8 __attribute__((ext_vector_type(8)));
typedef unsigned short u16x4 __attribute__((ext_vector_type(4)));

__device__ __forceinline__ unsigned short f2bf(float f) {
  unsigned int u = __builtin_bit_cast(unsigned int, f);
  u += 0x7fff + ((u >> 16) & 1);   // RNE; values are finite
  return (unsigned short)(u >> 16);
}
__device__ __forceinline__ float bf2f(unsigned short u) {
  return __builtin_bit_cast(float, (unsigned int)u << 16);
}

__device__ __forceinline__ u16x8 cvt8(const float* p) {
  f32x4 lo = *(const f32x4*)p;
  f32x4 hi = *(const f32x4*)(p + 4);
  u16x8 r;
#pragma unroll
  for (int j = 0; j < 4; j++) { r[j] = f2bf(lo[j]); r[4 + j] = f2bf(hi[j]); }
  return r;
}

// async 16B global->LDS copy. LDS dest must be wave-uniform base; HW adds
// lane*16. Global src is per-lane.
__device__ __forceinline__ void gload16(const void* g, void* l) {
  __builtin_amdgcn_global_load_lds(
      (const __attribute__((address_space(1))) void*)g,
      (__attribute__((address_space(3))) void*)l, 16, 0, 0);
}

// ---------------------------------------------------------------------------
// fp32 -> bf16 bulk convert. n8 = element count / 8. Memory-bound.
// ---------------------------------------------------------------------------
__global__ __launch_bounds__(256) void f32_to_bf16(
    const float* __restrict__ src, unsigned short* __restrict__ dst, int n8) {
  int i = blockIdx.x * 256 + threadIdx.x;
  const int stride = gridDim.x * 256;
  for (; i < n8; i += stride) {
    u16x8 v = cvt8(src + (size_t)i * 8);
    *(u16x8*)&dst[(size_t)i * 8] = v;
  }
}

// ---------------------------------------------------------------------------
// GEMM: C[M][N] = A[M][K] @ B[N][K]^T. A/B bf16; C bf16 or fp32.
// 128x128 tile, BK=32, 256 threads (4 waves, each 64x64 as 4x4 of 16x16x32).
// Staging: global_load_lds dwordx4, linear LDS.
// ---------------------------------------------------------------------------
template <bool COF32>
__global__ __launch_bounds__(256) void gemm_bf(
    const unsigned short* __restrict__ A, const unsigned short* __restrict__ B,
    void* __restrict__ Cv, int M, int N, int K) {
  __shared__ __align__(16) unsigned short Alds[128 * 32];
  __shared__ __align__(16) unsigned short Blds[128 * 32];

  const int tid  = threadIdx.x;
  const int lane = tid & 63;
  const int w    = tid >> 6;
  const int ln   = lane & 15;
  const int kq   = lane >> 4;
  const int m0 = blockIdx.y * 128;
  const int n0 = blockIdx.x * 128;
  const int m_base = (w >> 1) * 64;
  const int n_base = (w & 1) * 64;

  f32x4 acc[4][4];
#pragma unroll
  for (int i = 0; i < 4; i++)
#pragma unroll
    for (int j = 0; j < 4; j++) acc[i][j] = {0.f, 0.f, 0.f, 0.f};

  const int c0 = tid;          // chunk ids: [0,256) and [256,512)
  const int c1 = tid + 256;
  const unsigned short* Ag0 = A + (size_t)(m0 + (c0 >> 2)) * K + (c0 & 3) * 8;
  const unsigned short* Ag1 = A + (size_t)(m0 + (c1 >> 2)) * K + (c1 & 3) * 8;
  const unsigned short* Bg0 = B + (size_t)(n0 + (c0 >> 2)) * K + (c0 & 3) * 8;
  const unsigned short* Bg1 = B + (size_t)(n0 + (c1 >> 2)) * K + (c1 & 3) * 8;
  // wave-uniform LDS bases: chunk c lands at byte c*16 (= element c*8)
  unsigned short* lA0 = &Alds[(size_t)w * 512];
  unsigned short* lA1 = &Alds[2048 + (size_t)w * 512];
  unsigned short* lB0 = &Blds[(size_t)w * 512];
  unsigned short* lB1 = &Blds[2048 + (size_t)w * 512];

  const int nk = K >> 5;
  for (int kt = 0; kt < nk; kt++) {
    const int ko = kt * 32;
    gload16(Ag0 + ko, lA0);
    gload16(Ag1 + ko, lA1);
    gload16(Bg0 + ko, lB0);
    gload16(Bg1 + ko, lB1);
    __syncthreads();   // compiler drains vmcnt(0) before s_barrier

    bf16x8 af[4], bfr[4];
#pragma unroll
    for (int i = 0; i < 4; i++)
      af[i] = *(const bf16x8*)&Alds[(m_base + i * 16 + ln) * 32 + kq * 8];
#pragma unroll
    for (int j = 0; j < 4; j++)
      bfr[j] = *(const bf16x8*)&Blds[(n_base + j * 16 + ln) * 32 + kq * 8];
#pragma unroll
    for (int i = 0; i < 4; i++)
#pragma unroll
      for (int j = 0; j < 4; j++)
        acc[i][j] = __builtin_amdgcn_mfma_f32_16x16x32_bf16(af[i], bfr[j], acc[i][j], 0, 0, 0);
    __syncthreads();
  }

  // Epilogue. C/D layout (m89): col = ln, row = kq*4 + r.
#pragma unroll
  for (int i = 0; i < 4; i++) {
    const int row_base = m0 + m_base + i * 16 + kq * 4;
#pragma unroll
    for (int j = 0; j < 4; j++) {
      const int col = n0 + n_base + j * 16 + ln;
#pragma unroll
      for (int r = 0; r < 4; r++) {
        const size_t idx = (size_t)(row_base + r) * N + col;
        if (COF32) ((float*)Cv)[idx] = acc[i][j][r];
        else       ((unsigned short*)Cv)[idx] = f2bf(acc[i][j][r]);
      }
    }
  }
}

// ---------------------------------------------------------------------------
// Transposed flash attention. qkv: [B*T][6144] bf16 (q|k|v, 2048 each).
// Block: 128 q rows (qb), 8 waves; wave w owns q rows q0+w*16+ln.
// S^T = K.Q^T  : D[m=key=kq*4+r (per nt)][n=q=ln]
// O^T = V^T.P^T: D[m=d=nt*16+kq*4+r][n=q=ln]
// Grid 512 = 2 blocks/CU, all co-resident; decode balances per-CU pairs.
// ---------------------------------------------------------------------------
#define TSEQ 2048
#define CDIM 2048
#define QKVLD 6144
#define DH 128
#define NEG_BIG (-1.0e30f)
#define K_LD 136
#define VT_LD 76
#define P_LD 72

__global__ __launch_bounds__(512, 4) void attn(
    const unsigned short* __restrict__ qkv,
    unsigned short* __restrict__ y) {
  __shared__ __align__(16) unsigned short Klds[64 * K_LD];    // [key][d]  17408B
  __shared__ __align__(16) unsigned short Vt[DH * VT_LD];     // [d][key]  19456B
  __shared__ __align__(16) unsigned short Plds[8 * 16 * P_LD];// per-wave [q][key] 18432B

  const int tid  = threadIdx.x;
  const int lane = tid & 63;
  const int w    = tid >> 6;          // 0..7
  const int ln   = lane & 15;
  const int kq   = lane >> 4;

  // balanced decode: half 0 (b=0) heavy-first, half 1 (b=1) light-first,
  // so block i and block i+256 (round-robin CU pair) sum to constant work.
  const int idx  = blockIdx.x;
  const int half = idx >> 8;
  const int qbi  = idx & 15;
  const int qb   = half ? qbi : 15 - qbi;
  const int h    = (idx >> 4) & 15;
  const int b    = half;
  const int q0   = qb * 128;
  const int qrow = q0 + w * 16 + ln;      // this lane's q row (global in seq)

  const size_t baseQ = (size_t)b * TSEQ * QKVLD + (size_t)h * DH;
  const size_t baseK = baseQ + CDIM;
  const size_t baseV = baseQ + 2 * CDIM;

  // Q fragments (B-operand), pre-scaled by 1/sqrt(128).
  bf16x8 qf[4];
  {
    const float scale = 0.08838834764831845f;
    const unsigned short* qp = qkv + baseQ + (size_t)qrow * QKVLD + kq * 8;
#pragma unroll
    for (int kc = 0; kc < 4; kc++) {
      u16x8 raw = *(const u16x8*)(qp + kc * 32);
      u16x8 t;
#pragma unroll
      for (int j = 0; j < 8; j++) t[j] = f2bf(bf2f(raw[j]) * scale);
      qf[kc] = __builtin_bit_cast(bf16x8, t);
    }
  }

  // staging addresses (512 threads, 64x128 tile)
  const int kRow = tid >> 4;                 // [0,32): K key row
  const int kCol = (tid & 15) * 8;           // K d offset (16B)
  const int vK4  = (tid & 15) * 4;           // V: 4 consecutive keys
  const int vD0  = (tid >> 4) * 4;           // V: 4 d elems [0,128)
  const unsigned short* Kg = qkv + baseK + (size_t)kRow * QKVLD + kCol;
  const unsigned short* Vg = qkv + baseV + (size_t)vK4 * QKVLD + vD0;

  u16x8 kreg[2];
  u16x4 vreg[4];
#pragma unroll
  for (int it = 0; it < 2; it++)
    kreg[it] = *(const u16x8*)(Kg + (size_t)(it * 32) * QKVLD);
#pragma unroll
  for (int r = 0; r < 4; r++)
    vreg[r] = *(const u16x4*)(Vg + (size_t)r * QKVLD);

  f32x4 o[8];
#pragma unroll
  for (int i = 0; i < 8; i++) o[i] = {0.f, 0.f, 0.f, 0.f};
  float m = NEG_BIG, l = 0.f;
  unsigned short* pw = &Plds[w * 16 * P_LD];

  const int ktEnd   = 2 * qb + 2;
  const int myKtMax = (q0 + w * 16) >> 6;   // wave-uniform: 2qb + (w>=4)

  for (int kt = 0; kt < ktEnd; kt++) {
    __syncthreads();  // previous iteration's LDS reads done

    // commit prefetched tile to LDS
#pragma unroll
    for (int it = 0; it < 2; it++)
      *(u16x8*)&Klds[(kRow + it * 32) * K_LD + kCol] = kreg[it];
#pragma unroll
    for (int j = 0; j < 4; j++) {
      u16x4 t = {vreg[0][j], vreg[1][j], vreg[2][j], vreg[3][j]};
      *(u16x4*)&Vt[(vD0 + j) * VT_LD + vK4] = t;
    }
    __syncthreads();

    // prefetch next tile (no wait; overlaps compute)
    if (kt + 1 < ktEnd) {
      const size_t off = (size_t)(kt + 1) * 64 * QKVLD;
#pragma unroll
      for (int it = 0; it < 2; it++)
        kreg[it] = *(const u16x8*)(Kg + off + (size_t)(it * 32) * QKVLD);
#pragma unroll
      for (int r = 0; r < 4; r++)
        vreg[r] = *(const u16x4*)(Vg + off + (size_t)r * QKVLD);
    }

    if (kt > myKtMax) continue;   // wave-uniform: tile fully masked for this wave

    // --- S^T = K Q^T : s[nt][r] = S[key = kt*64+nt*16+kq*4+r][q = qrow] ---
    f32x4 s[4];
#pragma unroll
    for (int nt = 0; nt < 4; nt++) {
      s[nt] = {0.f, 0.f, 0.f, 0.f};
#pragma unroll
      for (int kc = 0; kc < 4; kc++) {
        bf16x8 kb = *(const bf16x8*)&Klds[(nt * 16 + ln) * K_LD + kc * 32 + kq * 8];
        s[nt] = __builtin_amdgcn_mfma_f32_16x16x32_bf16(kb, qf[kc], s[nt], 0, 0, 0);
      }
    }

    // --- causal mask (only on this wave's diagonal tile) ---
    if (kt == myKtMax) {
      const int kbase = kt * 64 + kq * 4;
#pragma unroll
      for (int nt = 0; nt < 4; nt++)
#pragma unroll
        for (int r = 0; r < 4; r++)
          if (kbase + nt * 16 + r > qrow) s[nt][r] = NEG_BIG;
    }

    // --- per-lane online softmax (lane's row spread over 4 kq groups) ---
    float mt;
    {
      f32x4 t01 = {fmaxf(s[0][0], s[0][1]), fmaxf(s[0][2], s[0][3]),
                   fmaxf(s[1][0], s[1][1]), fmaxf(s[1][2], s[1][3])};
      f32x4 t23 = {fmaxf(s[2][0], s[2][1]), fmaxf(s[2][2], s[2][3]),
                   fmaxf(s[3][0], s[3][1]), fmaxf(s[3][2], s[3][3])};
      f32x4 t = {fmaxf(t01[0], t01[1]), fmaxf(t01[2], t01[3]),
                 fmaxf(t23[0], t23[1]), fmaxf(t23[2], t23[3])};
      mt = fmaxf(fmaxf(t[0], t[1]), fmaxf(t[2], t[3]));
    }
    mt = fmaxf(mt, __shfl_xor(mt, 16, 64));
    mt = fmaxf(mt, __shfl_xor(mt, 32, 64));

    // T13 defer-max: keep old m when growth <= 8 (P bounded by e^8); skips
    // the O-rescale pass. Wave-uniform branch.
    const bool defer = __all(mt - m <= 8.0f);
    const float mn = defer ? m : fmaxf(m, mt);
    const float alpha = defer ? 1.0f : __expf(m - mn);
    m = mn;

    float ps = 0.f;
#pragma unroll
    for (int nt = 0; nt < 4; nt++) {
      u16x4 pbits;
#pragma unroll
      for (int r = 0; r < 4; r++) {
        const float p = __expf(s[nt][r] - mn);
        ps += p;
        pbits[r] = f2bf(p);
      }
      *(u16x4*)&pw[ln * P_LD + nt * 16 + kq * 4] = pbits;  // P[q=ln][key]
    }
    ps += __shfl_xor(ps, 16, 64);
    ps += __shfl_xor(ps, 32, 64);
    l = l * alpha + ps;

    if (!defer) {
#pragma unroll
      for (int i = 0; i < 8; i++)
#pragma unroll
        for (int r = 0; r < 4; r++) o[i][r] *= alpha;
    }

    // --- O^T += V^T P^T (P read back as B-frag; same-wave DS in order) ---
    bf16x8 pa[2];
#pragma unroll
    for (int kc = 0; kc < 2; kc++)
      pa[kc] = *(const bf16x8*)&pw[ln * P_LD + kc * 32 + kq * 8];
#pragma unroll
    for (int nt = 0; nt < 8; nt++)
#pragma unroll
      for (int kc = 0; kc < 2; kc++) {
        bf16x8 vb = *(const bf16x8*)&Vt[(nt * 16 + ln) * VT_LD + kc * 32 + kq * 8];
        o[nt] = __builtin_amdgcn_mfma_f32_16x16x32_bf16(vb, pa[kc], o[nt], 0, 0, 0);
      }
  }

  // --- epilogue: o[nt][r] = O[q=qrow][d = nt*16 + kq*4 + r] ---
  const float inv = 1.f / l;
  unsigned short* yp = y + (size_t)(b * TSEQ + qrow) * CDIM + (size_t)h * DH + kq * 4;
#pragma unroll
  for (int nt = 0; nt < 8; nt++) {
    u16x4 ov;
#pragma unroll
    for (int r = 0; r < 4; r++) ov[r] = f2bf(o[nt][r] * inv);
    *(u16x4*)(yp + nt * 16) = ov;
  }
}

extern "C" void kernel_launch(void* const* d_in, const int* in_sizes, int n_in,
                              void* d_out, int out_size, void* d_ws, size_t ws_size,
                              hipStream_t stream) {
  const float* x     = (const float*)d_in[0];  // fp32 [4096][2048]
  const float* Wqkv  = (const float*)d_in[1];  // fp32 [6144][2048]
  const float* Wproj = (const float*)d_in[2];  // fp32 [2048][2048]
  void* out = d_out;                                   // fp32 [4096][2048]

  unsigned short* qkv = (unsigned short*)d_ws;         // bf16, 48MB
  unsigned short* y   = qkv + (size_t)4096 * 6144;     // bf16, 16MB (aliases x_bf)
  unsigned short* xbf = y;                             // x_bf dead before attn writes y
  unsigned short* wbf = y + (size_t)4096 * 2048;       // 24MB (Wqkv_bf, then Wproj_bf)

  f32_to_bf16<<<dim3(2048), 256, 0, stream>>>(x, xbf, (4096 * 2048) / 8);
  f32_to_bf16<<<dim3(2048), 256, 0, stream>>>(Wqkv, wbf, (6144 * 2048) / 8);
  gemm_bf<false><<<dim3(48, 32), 256, 0, stream>>>(xbf, wbf, qkv, 4096, 6144, 2048);
  f32_to_bf16<<<dim3(2048), 256, 0, stream>>>(Wproj, wbf, (2048 * 2048) / 8);  // Wqkv_bf dead
  attn<<<dim3(512), 512, 0, stream>>>(qkv, y);
  gemm_bf<true><<<dim3(16, 32), 256, 0, stream>>>(y, wbf, out, 4096, 2048, 2048);
}